// Round 1
// baseline (1116.108 us; speedup 1.0000x reference)
//
#include <hip/hip_runtime.h>

// ---------------------------------------------------------------------------
// 2-layer GCN (PyG GCNConv semantics) on MI355X.
// Math: out = dinv .* segsum(dinv .* (h @ W)) + b, per layer, with self-loops.
// Strategy: build CSR (by dst) per call, fuse dinv into GEMM epilogues,
// gather-sum (no float atomics), fuse agg1+ReLU+GEMM2 to skip h1 in HBM.
// ---------------------------------------------------------------------------

static inline size_t align256(size_t x) { return (x + 255) & ~(size_t)255; }

__global__ void zero_k(int* __restrict__ p, int n) {
  int i = blockIdx.x * blockDim.x + threadIdx.x;
  if (i < n) p[i] = 0;
}

__global__ void count_k(const int* __restrict__ dst, int* __restrict__ counts, int E) {
  int e = blockIdx.x * blockDim.x + threadIdx.x;
  if (e < E) atomicAdd(&counts[dst[e]], 1);
}

__global__ void dinv_k(const int* __restrict__ counts, float* __restrict__ dinv, int n) {
  int i = blockIdx.x * blockDim.x + threadIdx.x;
  if (i < n) dinv[i] = rsqrtf((float)(counts[i] + 1));  // +1 self-loop
}

// Exclusive prefix sum of counts -> row_off. Single block, 1024 threads,
// wave-shuffle scan per 64, serial wave-sum combine, chunked over n.
__global__ __launch_bounds__(1024) void scan_k(const int* __restrict__ counts,
                                               int* __restrict__ row_off, int n) {
  __shared__ int wsums[16];
  __shared__ int carry_s;
  int t = threadIdx.x, lane = t & 63, wid = t >> 6;
  if (t == 0) carry_s = 0;
  __syncthreads();
  for (int base = 0; base < n; base += 1024) {
    int idx = base + t;
    int v = (idx < n) ? counts[idx] : 0;
    int incl = v;
#pragma unroll
    for (int off = 1; off < 64; off <<= 1) {
      int u = __shfl_up(incl, off, 64);
      if (lane >= off) incl += u;
    }
    if (lane == 63) wsums[wid] = incl;
    __syncthreads();
    int woff = 0;
    for (int w = 0; w < wid; ++w) woff += wsums[w];
    if (idx < n) row_off[idx] = carry_s + woff + (incl - v);
    __syncthreads();
    if (t == 0) {
      int tot = 0;
      for (int w = 0; w < 16; ++w) tot += wsums[w];
      carry_s += tot;
    }
    __syncthreads();
  }
}

__global__ void scatter_k(const int* __restrict__ src, const int* __restrict__ dst,
                          const int* __restrict__ row_off, int* __restrict__ cursor,
                          int* __restrict__ col, int E) {
  int e = blockIdx.x * blockDim.x + threadIdx.x;
  if (e < E) {
    int d = dst[e];
    int p = row_off[d] + atomicAdd(&cursor[d], 1);
    col[p] = src[e];
  }
}

// g1 = dinv .* (x @ W1).  Tile: 64 rows x 128 cols, K staged in 2x64 LDS chunks.
// 256 threads, each computes 4 rows x 8 cols.
__global__ __launch_bounds__(256) void gemm1_k(const float* __restrict__ x,
                                               const float* __restrict__ W,
                                               const float* __restrict__ dinv,
                                               float* __restrict__ g1, int n) {
  __shared__ float Xs[64][68];   // [row][k-local], pad 68 (16B-aligned rows, 2-way max)
  __shared__ float Ws[64][132];  // [k-local][col], pad 132
  int t = threadIdx.x;
  int row0 = blockIdx.x * 64;
  int cg = t & 15, rg = t >> 4;
  int c0 = cg * 8, r0 = rg * 4;

  float acc[4][8];
#pragma unroll
  for (int r = 0; r < 4; ++r)
#pragma unroll
    for (int c = 0; c < 8; ++c) acc[r][c] = 0.f;

  for (int ks = 0; ks < 2; ++ks) {
    __syncthreads();  // protect LDS reuse from previous compute phase
    // stage X chunk: 64 rows x 64 k = 1024 float4, 4 per thread
#pragma unroll
    for (int q = 0; q < 4; ++q) {
      int f = t + q * 256;
      int r = f >> 4, c4 = f & 15;
      int grow = row0 + r;
      float4 v = make_float4(0.f, 0.f, 0.f, 0.f);
      if (grow < n) v = *(const float4*)(x + (size_t)grow * 128 + ks * 64 + c4 * 4);
      *(float4*)&Xs[r][c4 * 4] = v;
    }
    // stage W chunk: 64 k x 128 cols = 2048 float4, 8 per thread
#pragma unroll
    for (int q = 0; q < 8; ++q) {
      int f = t + q * 256;
      int k = f >> 5, c4 = f & 31;
      float4 v = *(const float4*)(W + (size_t)(ks * 64 + k) * 128 + c4 * 4);
      *(float4*)&Ws[k][c4 * 4] = v;
    }
    __syncthreads();

#pragma unroll
    for (int k4 = 0; k4 < 16; ++k4) {
      float4 xv0 = *(const float4*)&Xs[r0 + 0][k4 * 4];
      float4 xv1 = *(const float4*)&Xs[r0 + 1][k4 * 4];
      float4 xv2 = *(const float4*)&Xs[r0 + 2][k4 * 4];
      float4 xv3 = *(const float4*)&Xs[r0 + 3][k4 * 4];
#pragma unroll
      for (int kk = 0; kk < 4; ++kk) {
        const float* wrow = &Ws[k4 * 4 + kk][0];
        float4 wa = *(const float4*)(wrow + c0);
        float4 wb = *(const float4*)(wrow + c0 + 4);
        float a0 = kk == 0 ? xv0.x : kk == 1 ? xv0.y : kk == 2 ? xv0.z : xv0.w;
        float a1 = kk == 0 ? xv1.x : kk == 1 ? xv1.y : kk == 2 ? xv1.z : xv1.w;
        float a2 = kk == 0 ? xv2.x : kk == 1 ? xv2.y : kk == 2 ? xv2.z : xv2.w;
        float a3 = kk == 0 ? xv3.x : kk == 1 ? xv3.y : kk == 2 ? xv3.z : xv3.w;
        float as[4] = {a0, a1, a2, a3};
#pragma unroll
        for (int r = 0; r < 4; ++r) {
          acc[r][0] += as[r] * wa.x; acc[r][1] += as[r] * wa.y;
          acc[r][2] += as[r] * wa.z; acc[r][3] += as[r] * wa.w;
          acc[r][4] += as[r] * wb.x; acc[r][5] += as[r] * wb.y;
          acc[r][6] += as[r] * wb.z; acc[r][7] += as[r] * wb.w;
        }
      }
    }
  }

#pragma unroll
  for (int r = 0; r < 4; ++r) {
    int grow = row0 + r0 + r;
    if (grow < n) {
      float s = dinv[grow];
      float4 va = make_float4(acc[r][0] * s, acc[r][1] * s, acc[r][2] * s, acc[r][3] * s);
      float4 vb = make_float4(acc[r][4] * s, acc[r][5] * s, acc[r][6] * s, acc[r][7] * s);
      float* o = g1 + (size_t)grow * 128 + c0;
      *(float4*)o = va;
      *(float4*)(o + 4) = vb;
    }
  }
}

// Fused: h1[i] = relu(dinv[i]*(sum_{j in N(i)} g1[j] + g1[i]) + b1);
//        g2[i] = dinv[i] * (h1[i] @ W2).   One 128-thread block per node.
__global__ __launch_bounds__(128) void agg1_k(const float* __restrict__ g1,
                                              const int* __restrict__ col,
                                              const int* __restrict__ row_off,
                                              const int* __restrict__ counts,
                                              const float* __restrict__ dinv,
                                              const float* __restrict__ b1,
                                              const float* __restrict__ W2,
                                              float* __restrict__ g2, int n) {
  __shared__ float W2s[128 * 40];  // row-major [c][o]
  __shared__ float h1s[128];
  __shared__ int cols_s[128];
  int i = blockIdx.x;
  int t = threadIdx.x;

  // stage W2 (20 KB), coalesced linear copy
#pragma unroll
  for (int q = 0; q < 40; ++q) W2s[t + 128 * q] = W2[t + 128 * q];

  int start = row_off[i];
  int cnt = counts[i];
  float di = dinv[i];
  float acc = g1[(size_t)i * 128 + t];  // self-loop term

  for (int base = 0; base < cnt; base += 128) {
    int m = min(128, cnt - base);
    __syncthreads();
    if (t < m) cols_s[t] = col[start + base + t];
    __syncthreads();
#pragma unroll 4
    for (int e = 0; e < m; ++e) {
      int j = cols_s[e];
      acc += g1[(size_t)j * 128 + t];
    }
  }

  float h = fmaxf(di * acc + b1[t], 0.f);
  h1s[t] = h;
  __syncthreads();

  if (t < 40) {
    float s = 0.f;
#pragma unroll 8
    for (int c = 0; c < 128; ++c) s += h1s[c] * W2s[c * 40 + t];
    g2[(size_t)i * 40 + t] = di * s;
  }
}

// out[i] = dinv[i]*(sum g2[j] + g2[i]) + b2.  One wave per node, lanes 0..39.
__global__ __launch_bounds__(64) void agg2_k(const float* __restrict__ g2,
                                             const int* __restrict__ col,
                                             const int* __restrict__ row_off,
                                             const int* __restrict__ counts,
                                             const float* __restrict__ dinv,
                                             const float* __restrict__ b2,
                                             float* __restrict__ out, int n) {
  __shared__ int cols_s[64];
  int i = blockIdx.x;
  int t = threadIdx.x;
  int start = row_off[i];
  int cnt = counts[i];
  float di = dinv[i];
  float acc = (t < 40) ? g2[(size_t)i * 40 + t] : 0.f;

  for (int base = 0; base < cnt; base += 64) {
    int m = min(64, cnt - base);
    __syncthreads();
    if (t < m) cols_s[t] = col[start + base + t];
    __syncthreads();
#pragma unroll 4
    for (int e = 0; e < m; ++e) {
      int j = cols_s[e];
      if (t < 40) acc += g2[(size_t)j * 40 + t];
    }
  }
  if (t < 40) out[(size_t)i * 40 + t] = di * acc + b2[t];
}

extern "C" void kernel_launch(void* const* d_in, const int* in_sizes, int n_in,
                              void* d_out, int out_size, void* d_ws, size_t ws_size,
                              hipStream_t stream) {
  const float* x  = (const float*)d_in[0];
  const int*   ei = (const int*)d_in[1];
  const float* W1 = (const float*)d_in[2];
  const float* b1 = (const float*)d_in[3];
  const float* W2 = (const float*)d_in[4];
  const float* b2 = (const float*)d_in[5];
  float* out = (float*)d_out;

  const int N = in_sizes[0] / 128;
  const int E = in_sizes[1] / 2;
  const int* src = ei;
  const int* dst = ei + E;

  size_t off = 0;
  auto alloc = [&](size_t bytes) {
    char* p = (char*)d_ws + off;
    off = align256(off + bytes);
    return (void*)p;
  };
  float* dinv   = (float*)alloc((size_t)N * 4);
  int*   counts = (int*)alloc((size_t)N * 4);
  int*   cursor = (int*)alloc((size_t)N * 4);
  int*   rowoff = (int*)alloc((size_t)N * 4);
  int*   col    = (int*)alloc((size_t)E * 4);
  float* g1     = (float*)alloc((size_t)N * 128 * 4);
  float* g2     = (float*)alloc((size_t)N * 40 * 4);
  if (off > ws_size) return;  // workspace too small; fail loudly via wrong output

  int gE = (E + 255) / 256;
  int gN = (N + 255) / 256;

  zero_k<<<gN, 256, 0, stream>>>(counts, N);
  zero_k<<<gN, 256, 0, stream>>>(cursor, N);
  count_k<<<gE, 256, 0, stream>>>(dst, counts, E);
  dinv_k<<<gN, 256, 0, stream>>>(counts, dinv, N);
  scan_k<<<1, 1024, 0, stream>>>(counts, rowoff, N);
  scatter_k<<<gE, 256, 0, stream>>>(src, dst, rowoff, cursor, col, E);
  gemm1_k<<<(N + 63) / 64, 256, 0, stream>>>(x, W1, dinv, g1, N);
  agg1_k<<<N, 128, 0, stream>>>(g1, col, rowoff, counts, dinv, b1, W2, g2, N);
  agg2_k<<<N, 64, 0, stream>>>(g2, col, rowoff, counts, dinv, b2, out, N);
}